// Round 10
// baseline (960.037 us; speedup 1.0000x reference)
//
#include <hip/hip_runtime.h>
#include <cstdint>
#include <cstddef>

// ---------------- problem constants ----------------
#define CD    512
#define HD    64
#define C1D   358
#define C2D   154
#define BB    8
#define PP    4096
#define NT    32768
#define LKK   256

typedef __attribute__((ext_vector_type(8))) short bf16x8;
typedef __attribute__((ext_vector_type(4))) float f32x4;

__device__ __forceinline__ unsigned short f2bf(float f) {
    union { float f; unsigned u; } v; v.f = f;
    unsigned r = v.u + 0x7FFF + ((v.u >> 16) & 1);
    return (unsigned short)(r >> 16);
}
__device__ __forceinline__ float bf2f(unsigned short s) {
    union { unsigned u; float f; } v; v.u = ((unsigned)s) << 16;
    return v.f;
}

#define GL_LDS16(gp, lp) __builtin_amdgcn_global_load_lds( \
    (const __attribute__((address_space(1))) unsigned int*)(gp), \
    (__attribute__((address_space(3))) unsigned int*)(lp), 16, 0, 0)

// -------- all weight casts + pads in ONE dispatch (2,424,832 threads exact) --------
__global__ __launch_bounds__(256)
void cast_all(const float* __restrict__ hinw, const float* __restrict__ houtw,
              const float* __restrict__ vinw, const float* __restrict__ voutw,
              const float* __restrict__ hfcw, const float* __restrict__ vfcw,
              unsigned short* __restrict__ Whin, unsigned short* __restrict__ Whout,
              unsigned short* __restrict__ Wvin, unsigned short* __restrict__ Wvout,
              unsigned short* __restrict__ Whfc, unsigned short* __restrict__ Wvfc) {
    int i = blockIdx.x * 256 + threadIdx.x;
    if (i < 786432) { Whin[i] = f2bf(hinw[i]); return; }
    i -= 786432;
    if (i < 262144) { Whout[i] = f2bf(houtw[i]); return; }
    i -= 262144;
    if (i < 786432) { Wvin[i] = f2bf(vinw[i]); return; }
    i -= 786432;
    if (i < 262144) { Wvout[i] = f2bf(voutw[i]); return; }
    i -= 262144;
    if (i < 196608) {   // hfc pad [384][512], Nreal=358
        int r = i >> 9, c = i & 511;
        Whfc[i] = (r < C1D) ? f2bf(hfcw[r * CD + c]) : 0;
        return;
    }
    i -= 196608;
    {                   // vfc pad [256][512], Nreal=154
        int r = i >> 9, c = i & 511;
        Wvfc[i] = (r < C2D) ? f2bf(vfcw[r * CD + c]) : 0;
    }
}

// -------- one pass over x -> Xt[(p*8+b)*512+c] AND Xv[t'*512+c] (bf16) --------
__global__ __launch_bounds__(256)
void transpose_both(const float* __restrict__ x, unsigned short* __restrict__ Xt,
                    unsigned short* __restrict__ Xv) {
    __shared__ float tile[32][33];
    const int b  = blockIdx.z;
    const int p0 = blockIdx.x << 5;
    const int c0 = blockIdx.y << 5;
    const int tx = threadIdx.x;   // 32
    const int ty = threadIdx.y;   // 8
#pragma unroll
    for (int i = 0; i < 4; i++) {
        int c = c0 + ty + (i << 3);
        tile[ty + (i << 3)][tx] = x[((size_t)b * CD + c) * PP + p0 + tx];
    }
    __syncthreads();
#pragma unroll
    for (int i = 0; i < 4; i++) {
        int p  = p0 + ty + (i << 3);
        int c  = c0 + tx;
        unsigned short v = f2bf(tile[tx][ty + (i << 3)]);
        Xt[((size_t)p * BB + b) * CD + c] = v;
        int hh = p >> 6, ww = p & 63;
        int nw = ww >> 2, wd = ww & 3;
        int tp = ((hh << 2) + wd) * 128 + (b << 4) + nw;
        Xv[(size_t)tp * CD + c] = v;
    }
}

// ---- pool: Xp[(b*256+k)*512+c] = mean of 4x4 window (bf16 in/out) ----
__global__ __launch_bounds__(512)
void pool_from_xt(const unsigned short* __restrict__ Xt, unsigned short* __restrict__ Xp) {
    const int u = blockIdx.x;          // b*256+k
    const int c = threadIdx.x;         // 512
    const int b = u >> 8, k = u & 255;
    const int ph = k >> 4, pw = k & 15;
    float s = 0.f;
#pragma unroll
    for (int dy = 0; dy < 4; dy++)
#pragma unroll
        for (int dx = 0; dx < 4; dx++) {
            int p = ((ph << 2) + dy) * 64 + (pw << 2) + dx;
            s += bf2f(Xt[((size_t)p * BB + b) * CD + c]);
        }
    Xp[(size_t)u * CD + c] = f2bf(s * (1.f / 16.f));
}

// ---------------- MFMA GEMM core ----------------
__device__ __forceinline__ void stage_tile(const unsigned short* __restrict__ g,
                                           unsigned short* l, int K, int tid) {
#pragma unroll
    for (int i = 0; i < 4; i++) {
        int c  = i * 256 + tid;           // 16B chunk id, 0..1023
        int r  = c >> 3;                  // row 0..127
        int ko = (c & 7) << 3;            // k offset 0..56
        GL_LDS16(g + (size_t)r * K + ko, l + c * 8);
    }
}

__device__ __forceinline__ void gemm_core(const unsigned short* __restrict__ A,
                                          const unsigned short* __restrict__ W,
                                          int K, int row0, int col0, int tid,
                                          unsigned short* ldsA, unsigned short* ldsB,
                                          f32x4 acc[4][4]) {
    const int lane = tid & 63;
    const int wid  = tid >> 6;
    const int wr = wid >> 1, wc = wid & 1;
    const int lr = lane & 15, lg = lane >> 4;

    f32x4 zero = {0.f, 0.f, 0.f, 0.f};
#pragma unroll
    for (int m = 0; m < 4; m++)
#pragma unroll
        for (int n = 0; n < 4; n++) acc[m][n] = zero;

    const unsigned short* Ab = A + (size_t)row0 * K;
    const unsigned short* Wb = W + (size_t)col0 * K;

    stage_tile(Ab, ldsA, K, tid);
    stage_tile(Wb, ldsB, K, tid);
    __syncthreads();

    const int NTILES = K >> 6;
    int buf = 0;
    for (int t = 0; t < NTILES; t++) {
        if (t + 1 < NTILES) {
            stage_tile(Ab + ((t + 1) << 6), ldsA + ((buf ^ 1) << 13), K, tid);
            stage_tile(Wb + ((t + 1) << 6), ldsB + ((buf ^ 1) << 13), K, tid);
        }
#pragma unroll
        for (int kk = 0; kk < 2; kk++) {
            bf16x8 af[4], bfr[4];
#pragma unroll
            for (int m = 0; m < 4; m++)
                af[m] = *reinterpret_cast<const bf16x8*>(
                    ldsA + (buf << 13) + (wr * 64 + m * 16 + lr) * 64 + kk * 32 + lg * 8);
#pragma unroll
            for (int n = 0; n < 4; n++)
                bfr[n] = *reinterpret_cast<const bf16x8*>(
                    ldsB + (buf << 13) + (wc * 64 + n * 16 + lr) * 64 + kk * 32 + lg * 8);
#pragma unroll
            for (int m = 0; m < 4; m++)
#pragma unroll
                for (int n = 0; n < 4; n++)
                    acc[m][n] = __builtin_amdgcn_mfma_f32_16x16x32_bf16(af[m], bfr[n], acc[m][n], 0, 0, 0);
        }
        __syncthreads();
        buf ^= 1;
    }
}

// plain epilogue: optional fp32 + bf16 outputs, col mask for padded N
__global__ __launch_bounds__(256)
void gemm_mfma(const unsigned short* __restrict__ A, const unsigned short* __restrict__ W,
               const float* __restrict__ bias,
               float* __restrict__ Cf, unsigned short* __restrict__ Cb,
               int M, int K, int Nreal) {
    __shared__ unsigned short ldsA[2][128][64];
    __shared__ unsigned short ldsB[2][128][64];
    const int tid = threadIdx.x;
    const int lane = tid & 63, wid = tid >> 6;
    const int wr = wid >> 1, wc = wid & 1;
    const int lr = lane & 15, lg = lane >> 4;
    const int row0 = blockIdx.y << 7;
    const int col0 = blockIdx.x << 7;
    f32x4 acc[4][4];
    gemm_core(A, W, K, row0, col0, tid, &ldsA[0][0][0], &ldsB[0][0][0], acc);

#pragma unroll
    for (int n = 0; n < 4; n++) {
        int col = col0 + wc * 64 + n * 16 + lr;
        bool cok = col < Nreal;
        float bv = cok ? bias[col] : 0.f;
#pragma unroll
        for (int m = 0; m < 4; m++) {
            int row = row0 + wr * 64 + m * 16 + lg * 4;
            if (cok) {
#pragma unroll
                for (int i = 0; i < 4; i++) {
                    float v = acc[m][n][i] + bv;
                    if (Cf) Cf[(size_t)(row + i) * Nreal + col] = v;
                    if (Cb) Cb[(size_t)(row + i) * Nreal + col] = f2bf(v);
                }
            }
        }
    }
}

// segmented epilogue: col>>9 selects destination buffer (each [M][512] bf16)
__global__ __launch_bounds__(256)
void gemm_mfma_seg(const unsigned short* __restrict__ A, const unsigned short* __restrict__ W,
                   const float* __restrict__ bias,
                   unsigned short* __restrict__ D0, unsigned short* __restrict__ D1,
                   unsigned short* __restrict__ D2, int M, int K) {
    __shared__ unsigned short ldsA[2][128][64];
    __shared__ unsigned short ldsB[2][128][64];
    const int tid = threadIdx.x;
    const int lane = tid & 63, wid = tid >> 6;
    const int wr = wid >> 1, wc = wid & 1;
    const int lr = lane & 15, lg = lane >> 4;
    const int row0 = blockIdx.y << 7;
    const int col0 = blockIdx.x << 7;
    f32x4 acc[4][4];
    gemm_core(A, W, K, row0, col0, tid, &ldsA[0][0][0], &ldsB[0][0][0], acc);

#pragma unroll
    for (int n = 0; n < 4; n++) {
        int col = col0 + wc * 64 + n * 16 + lr;
        int seg = col >> 9, c2 = col & 511;
        unsigned short* dst = (seg == 0) ? D0 : ((seg == 1) ? D1 : D2);
        float bv = bias[col];
#pragma unroll
        for (int m = 0; m < 4; m++) {
            int row = row0 + wr * 64 + m * 16 + lg * 4;
#pragma unroll
            for (int i = 0; i < 4; i++)
                dst[(size_t)(row + i) * CD + c2] = f2bf(acc[m][n][i] + bv);
        }
    }
}

// vertical out-proj epilogue: rows are t' indices; store permuted to t order.
// t' = (hh*4+wd)*128 + b*16 + nw  ->  t = (hh*64 + nw*4 + wd)*8 + b
__global__ __launch_bounds__(256)
void gemm_mfma_vperm(const unsigned short* __restrict__ A, const unsigned short* __restrict__ W,
                     const float* __restrict__ bias,
                     float* __restrict__ Cf, unsigned short* __restrict__ Cb, int K) {
    __shared__ unsigned short ldsA[2][128][64];
    __shared__ unsigned short ldsB[2][128][64];
    const int tid = threadIdx.x;
    const int lane = tid & 63, wid = tid >> 6;
    const int wr = wid >> 1, wc = wid & 1;
    const int lr = lane & 15, lg = lane >> 4;
    const int row0 = blockIdx.y << 7;
    const int col0 = blockIdx.x << 7;
    f32x4 acc[4][4];
    gemm_core(A, W, K, row0, col0, tid, &ldsA[0][0][0], &ldsB[0][0][0], acc);

#pragma unroll
    for (int n = 0; n < 4; n++) {
        int col = col0 + wc * 64 + n * 16 + lr;
        float bv = bias[col];
#pragma unroll
        for (int m = 0; m < 4; m++) {
            int rbase = row0 + wr * 64 + m * 16 + lg * 4;
#pragma unroll
            for (int i = 0; i < 4; i++) {
                int r = rbase + i;
                int s = r >> 7, rem = r & 127;
                int b = rem >> 4, nw = rem & 15;
                int hh = s >> 2, wd = s & 3;
                int t = (((hh << 6) + (nw << 2) + wd) << 3) + b;
                float v = acc[m][n][i] + bv;
                Cf[(size_t)t * CD + col] = v;
                Cb[(size_t)t * CD + col] = f2bf(v);
            }
        }
    }
}

// ---- FC epilogue fused with concat/residual/stats ----
// A rows are t = p*8+b tokens. Output written DIRECTLY to att[b][chBase+ch][p]
// (b,c,h,w layout), residual r = v + x added, per-(block,b) partial sums of
// r and r^2 stored to PS/PQ[bid*8+b]. Padded cols (>= Nreal) masked.
__global__ __launch_bounds__(256)
void gemm_mfma_att(const unsigned short* __restrict__ A, const unsigned short* __restrict__ W,
                   const float* __restrict__ bias, const float* __restrict__ x,
                   float* __restrict__ att, float* __restrict__ PS, float* __restrict__ PQ,
                   int K, int Nreal, int chBase, int bidBase) {
    __shared__ unsigned short ldsA[2][128][64];
    __shared__ unsigned short ldsB[2][128][64];
    __shared__ float scratch[128][129];
    __shared__ float bsum[8], bsq[8];
    const int tid = threadIdx.x;
    const int lane = tid & 63, wid = tid >> 6;
    const int wr = wid >> 1, wc = wid & 1;
    const int lr = lane & 15, lg = lane >> 4;
    const int row0 = blockIdx.y << 7;
    const int col0 = blockIdx.x << 7;
    f32x4 acc[4][4];
    gemm_core(A, W, K, row0, col0, tid, &ldsA[0][0][0], &ldsB[0][0][0], acc);

    if (tid < 8) { bsum[tid] = 0.f; bsq[tid] = 0.f; }
    // store tile (+bias) to padded LDS scratch: [t_local][ch_local]
#pragma unroll
    for (int n = 0; n < 4; n++) {
        int ch_l = wc * 64 + n * 16 + lr;
        int col  = col0 + ch_l;
        float bv = (col < Nreal) ? bias[col] : 0.f;
#pragma unroll
        for (int m = 0; m < 4; m++) {
            int t_l = wr * 64 + m * 16 + lg * 4;
#pragma unroll
            for (int i = 0; i < 4; i++)
                scratch[t_l + i][ch_l] = acc[m][n][i] + bv;
        }
    }
    __syncthreads();

    // transposed read-out: p-contiguous lanes, write att + residual stats
    const int p0 = row0 >> 3;
    for (int b = 0; b < 8; b++) {
        float s = 0.f, q = 0.f;
        for (int it = 0; it < 8; it++) {
            int rem  = it * 256 + tid;      // 0..2047
            int ch_l = rem >> 4;
            int p_l  = rem & 15;
            float v = scratch[p_l * 8 + b][ch_l];
            int ch = col0 + ch_l;
            if (ch < Nreal) {
                size_t o = ((size_t)b * CD + chBase + ch) * PP + p0 + p_l;
                att[o] = v;
                float r = v + x[o];
                s += r; q += r * r;
            }
        }
        for (int off = 32; off; off >>= 1) {
            s += __shfl_xor(s, off);
            q += __shfl_xor(q, off);
        }
        if (lane == 0) { atomicAdd(&bsum[b], s); atomicAdd(&bsq[b], q); }
    }
    __syncthreads();
    if (tid < 8) {
        int bid = bidBase + blockIdx.y * gridDim.x + blockIdx.x;
        PS[bid * 8 + tid] = bsum[tid];
        PQ[bid * 8 + tid] = bsq[tid];
    }
}

// ---------------- MFMA fused attention (Lk=256, D=64) ----------------
__global__ __launch_bounds__(512)
void attn_mfma(const unsigned short* __restrict__ Q, const unsigned short* __restrict__ Kp,
               const unsigned short* __restrict__ Vp, unsigned short* __restrict__ O,
               int QT, int QB, int KT, int KB) {
    __shared__ unsigned short Kb[256][72];    // [k][d], +8 pad
    __shared__ unsigned short Vt[64][264];    // [d][k], +8 pad
    __shared__ unsigned short Pl[8][16][264]; // per-wave P tile
    const int tid  = threadIdx.x;
    const int lane = tid & 63;
    const int w    = tid >> 6;
    const int lr = lane & 15, lg = lane >> 4;
    const int bh = blockIdx.y, bi = bh >> 3, h = bh & 7;
    const int q0 = blockIdx.x << 7;

    // stage K and V^T
    for (int idx = tid; idx < 8192; idx += 512) {
        int k  = idx >> 5;
        int d2 = (idx & 31) << 1;
        size_t grow = ((size_t)k * KT + (size_t)bi * KB) * CD + h * HD + d2;
        unsigned int kv = *reinterpret_cast<const unsigned int*>(&Kp[grow]);
        unsigned int vv = *reinterpret_cast<const unsigned int*>(&Vp[grow]);
        Kb[k][d2]     = (unsigned short)(kv & 0xffff);
        Kb[k][d2 + 1] = (unsigned short)(kv >> 16);
        Vt[d2][k]     = (unsigned short)(vv & 0xffff);
        Vt[d2 + 1][k] = (unsigned short)(vv >> 16);
    }
    __syncthreads();

    const int qrow = q0 + w * 16 + lr;
    const size_t qbase = ((size_t)qrow * QT + (size_t)bi * QB) * CD + h * HD;
    bf16x8 qf0 = *reinterpret_cast<const bf16x8*>(&Q[qbase + lg * 8]);
    bf16x8 qf1 = *reinterpret_cast<const bf16x8*>(&Q[qbase + 32 + lg * 8]);

    f32x4 zero = {0.f, 0.f, 0.f, 0.f};
    f32x4 sacc[16];
#pragma unroll
    for (int t = 0; t < 16; t++) sacc[t] = zero;
#pragma unroll
    for (int t = 0; t < 16; t++) {
        bf16x8 kb0 = *reinterpret_cast<const bf16x8*>(&Kb[t * 16 + lr][lg * 8]);
        bf16x8 kb1 = *reinterpret_cast<const bf16x8*>(&Kb[t * 16 + lr][32 + lg * 8]);
        sacc[t] = __builtin_amdgcn_mfma_f32_16x16x32_bf16(qf0, kb0, sacc[t], 0, 0, 0);
        sacc[t] = __builtin_amdgcn_mfma_f32_16x16x32_bf16(qf1, kb1, sacc[t], 0, 0, 0);
    }
#pragma unroll
    for (int t = 0; t < 16; t++) sacc[t] = sacc[t] * 0.125f;

    float mrow[4] = {-1e30f, -1e30f, -1e30f, -1e30f};
#pragma unroll
    for (int t = 0; t < 16; t++)
#pragma unroll
        for (int i = 0; i < 4; i++) mrow[i] = fmaxf(mrow[i], sacc[t][i]);
#pragma unroll
    for (int i = 0; i < 4; i++) {
        mrow[i] = fmaxf(mrow[i], __shfl_xor(mrow[i], 1));
        mrow[i] = fmaxf(mrow[i], __shfl_xor(mrow[i], 2));
        mrow[i] = fmaxf(mrow[i], __shfl_xor(mrow[i], 4));
        mrow[i] = fmaxf(mrow[i], __shfl_xor(mrow[i], 8));
    }
    float ssum[4] = {0.f, 0.f, 0.f, 0.f};
#pragma unroll
    for (int t = 0; t < 16; t++)
#pragma unroll
        for (int i = 0; i < 4; i++) {
            float p = __expf(sacc[t][i] - mrow[i]);
            sacc[t][i] = p;
            ssum[i] += p;
        }
#pragma unroll
    for (int i = 0; i < 4; i++) {
        ssum[i] += __shfl_xor(ssum[i], 1);
        ssum[i] += __shfl_xor(ssum[i], 2);
        ssum[i] += __shfl_xor(ssum[i], 4);
        ssum[i] += __shfl_xor(ssum[i], 8);
    }
    float rinv[4];
#pragma unroll
    for (int i = 0; i < 4; i++) rinv[i] = 1.f / ssum[i];

#pragma unroll
    for (int t = 0; t < 16; t++)
#pragma unroll
        for (int i = 0; i < 4; i++)
            Pl[w][lg * 4 + i][t * 16 + lr] = f2bf(sacc[t][i] * rinv[i]);

    f32x4 oacc[4];
#pragma unroll
    for (int n = 0; n < 4; n++) oacc[n] = zero;
#pragma unroll
    for (int ks = 0; ks < 8; ks++) {
        bf16x8 pa = *reinterpret_cast<const bf16x8*>(&Pl[w][lr][ks * 32 + lg * 8]);
#pragma unroll
        for (int n = 0; n < 4; n++) {
            bf16x8 vb = *reinterpret_cast<const bf16x8*>(&Vt[n * 16 + lr][ks * 32 + lg * 8]);
            oacc[n] = __builtin_amdgcn_mfma_f32_16x16x32_bf16(pa, vb, oacc[n], 0, 0, 0);
        }
    }
#pragma unroll
    for (int n = 0; n < 4; n++)
#pragma unroll
        for (int i = 0; i < 4; i++) {
            int qr2 = q0 + w * 16 + lg * 4 + i;
            size_t ob = ((size_t)qr2 * QT + (size_t)bi * QB) * CD + h * HD + n * 16 + lr;
            O[ob] = f2bf(oacc[n][i]);
        }
}

// ---- final reduce: wave b sums its 1280 partials -> mu, inv-std ----
__global__ __launch_bounds__(512)
void stats_final3(const float* __restrict__ PS, const float* __restrict__ PQ,
                  float* __restrict__ stats) {
    const int w    = threadIdx.x >> 6;   // 8 waves -> batch index
    const int lane = threadIdx.x & 63;
    float s = 0.f, q = 0.f;
    for (int i = lane; i < 1280; i += 64) {
        s += PS[i * 8 + w];
        q += PQ[i * 8 + w];
    }
    for (int off = 32; off; off >>= 1) {
        s += __shfl_xor(s, off);
        q += __shfl_xor(q, off);
    }
    if (lane == 0) {
        const float n = (float)CD * (float)PP;
        float mu  = s / n;
        float var = q / n - mu * mu;
        stats[16 + w] = mu;
        stats[24 + w] = 1.f / sqrtf(var + 1e-5f);
    }
}

__global__ __launch_bounds__(256)
void norm_kernel(const float* __restrict__ attn, const float* __restrict__ x,
                 const float* __restrict__ stats, float* __restrict__ out) {
    size_t i = ((size_t)blockIdx.x * blockDim.x + threadIdx.x) * 4;
    int b = (int)(i >> 21);
    float mu  = stats[16 + b];
    float inv = stats[24 + b];
    const float4 a4 = *reinterpret_cast<const float4*>(attn + i);
    const float4 x4 = *reinterpret_cast<const float4*>(x + i);
    float4 r;
    r.x = (a4.x + x4.x - mu) * inv;
    r.y = (a4.y + x4.y - mu) * inv;
    r.z = (a4.z + x4.z - mu) * inv;
    r.w = (a4.w + x4.w - mu) * inv;
    *reinterpret_cast<float4*>(out + i) = r;
}

// ---------------- host launch ----------------
extern "C" void kernel_launch(void* const* d_in, const int* in_sizes, int n_in,
                              void* d_out, int out_size, void* d_ws, size_t ws_size,
                              hipStream_t stream) {
    const float* x     = (const float*)d_in[0];
    const float* hinw  = (const float*)d_in[1];
    const float* hinb  = (const float*)d_in[2];
    const float* houtw = (const float*)d_in[3];
    const float* houtb = (const float*)d_in[4];
    const float* vinw  = (const float*)d_in[5];
    const float* vinb  = (const float*)d_in[6];
    const float* voutw = (const float*)d_in[7];
    const float* voutb = (const float*)d_in[8];
    const float* hfcw  = (const float*)d_in[9];
    const float* hfcb  = (const float*)d_in[10];
    const float* vfcw  = (const float*)d_in[11];
    const float* vfcb  = (const float*)d_in[12];

    char* wsb = (char*)d_ws;
    unsigned short* R0  = (unsigned short*)(wsb);               // Xt -> HAXB -> KVb
    unsigned short* R1  = (unsigned short*)(wsb + 33554432);    // Q/O both branches
    unsigned short* R2  = (unsigned short*)(wsb + 67108864);    // Xv -> VAXB
    unsigned short* R3  = (unsigned short*)(wsb + 100663296);   // VVb
    unsigned short* XP  = (unsigned short*)(wsb + 134217728);
    unsigned short* KHb = (unsigned short*)(wsb + 136314880);
    unsigned short* VHb = (unsigned short*)(wsb + 138412032);
    unsigned short* Whin  = (unsigned short*)(wsb + 207618048);  // [1536][512]
    unsigned short* Whout = Whin + 786432;                       // [512][512]
    unsigned short* Wvin  = Whout + 262144;                      // [1536][512]
    unsigned short* Wvout = Wvin + 786432;                       // [512][512]
    unsigned short* Whfc  = Wvout + 262144;                      // [384][512] padded
    unsigned short* Wvfc  = Whfc + 196608;                       // [256][512] padded
    float* STATS = (float*)(wsb + 212467712);                    // 32 floats
    float* PS    = (float*)(wsb + 212471808);                    // 10240 floats
    float* PQ    = PS + 10240;                                   // 10240 floats

    float* out_res = (float*)d_out;
    float* out_hax = out_res + 16777216;
    float* out_vax = out_res + 33554432;
    float* out_att = out_res + 50331648;

    // ---- weights (1 dispatch) ----
    cast_all<<<9472, 256, 0, stream>>>(hinw, houtw, vinw, voutw, hfcw, vfcw,
                                       Whin, Whout, Wvin, Wvout, Whfc, Wvfc);

    const dim3 tb(32, 8, 1);

    // ---- shared input prep: one pass over x ----
    transpose_both<<<dim3(128, 16, 8), tb, 0, stream>>>(x, R0, R2);       // Xt + Xv
    pool_from_xt<<<2048, 512, 0, stream>>>(R0, XP);

    // ---- horizontal branch ----
    gemm_mfma<<<dim3(4, 256), 256, 0, stream>>>(R0, Whin, hinb, nullptr, R1, NT, CD, CD);      // QH
    gemm_mfma_seg<<<dim3(8, 16), 256, 0, stream>>>(XP, Whin + 262144, hinb + 512,
                                                   KHb, VHb, nullptr, 2048, CD);               // KH|VH
    attn_mfma<<<dim3(32, 64), 512, 0, stream>>>(R1, KHb, VHb, R1, BB, 1, 1, 256);              // OH in-place
    gemm_mfma<<<dim3(4, 256), 256, 0, stream>>>(R1, Whout, houtb, out_hax, R0, NT, CD, CD);    // ha_x (+bf16)
    gemm_mfma_att<<<dim3(3, 256), 256, 0, stream>>>(R0, Whfc, hfcb, x, out_att, PS, PQ,
                                                    CD, C1D, 0, 0);                            // HA -> att + stats

    // ---- vertical branch ----
    gemm_mfma_seg<<<dim3(12, 256), 256, 0, stream>>>(R2, Wvin, vinb, R1, R0, R3, NT, CD);      // QV|KV|VV
    attn_mfma<<<dim3(2, 1024), 512, 0, stream>>>(R1, R0, R3, R1, 128, 1, 128, 1);              // OV in-place
    gemm_mfma_vperm<<<dim3(4, 256), 256, 0, stream>>>(R1, Wvout, voutb, out_vax, R2, CD);      // va_x (+bf16), permuted
    gemm_mfma_att<<<dim3(2, 256), 256, 0, stream>>>(R2, Wvfc, vfcb, x, out_att, PS, PQ,
                                                    CD, C2D, C1D, 768);                        // VA -> att + stats

    // ---- final layernorm ----
    stats_final3<<<1, 512, 0, stream>>>(PS, PQ, STATS);
    norm_kernel<<<16384, 256, 0, stream>>>(out_att, x, STATS, out_res);
}